// Round 9
// baseline (139.368 us; speedup 1.0000x reference)
//
#include <hip/hip_runtime.h>

// Problem dims (hard-coded in reference)
#define DD   768
#define NN   512
#define MM   512

#define PRE_K 2.88539008177792681472f   // 2*log2(e)

typedef _Float16 h8 __attribute__((ext_vector_type(8)));  // 8 f16 (4 VGPRs)
typedef __attribute__((ext_vector_type(4))) float f32x4;  // MFMA C/D

__device__ __forceinline__ float fexp(float x) { return __builtin_amdgcn_exp2f(x); }
__device__ __forceinline__ float frcp(float x) { return __builtin_amdgcn_rcpf(x); }
// tanh(x) = 1 - 2/(1 + e^{2x}); saturates correctly via exp2->inf/0 + rcp.
__device__ __forceinline__ float fast_tanh(float x) {
  return 1.0f - 2.0f * frcp(fexp(PRE_K * x) + 1.0f);
}
// Ledger: R13 keep HW trans. R14-R16: Q-fusion into main lost. R17 mega-kernel
// catastrophic. R18 bounds(256,8) -> spills. R19(R6, BEST 131.1): main 44.8 @
// occ 40% = trans-issue floor, FROZEN. R20(R7): BK64 neutral. R21(R8): prep
// deleted, in-GEMM convert — neutral-negative (136.5). Support is ~86us across
// wildly different structures; decompositions contradictory. R22(this) is a
// MEASUREMENT round: R6 build verbatim + main and mfma2 each split into two
// z-range dispatches. Main halves ~23us lower the top-5 visibility threshold
// so any support kernel >23us surfaces with its true duration; Δtotal vs
// 131.1 measures 2x per-dispatch overhead + ~4us known split cost.

// fp32 -> f16 hi/lo split (pair covers ~21 mantissa bits)
__device__ __forceinline__ void splitf(float x, ushort& h, ushort& l) {
  const _Float16 hh = (_Float16)x;
  const _Float16 ll = (_Float16)(x - (float)hh);
  h = __builtin_bit_cast(unsigned short, hh);
  l = __builtin_bit_cast(unsigned short, ll);
}

// ---- fused prep (R0 verbatim) ----------------------------------------------
// blocks [0,1344): elementwise f16 hi/lo split of text/visual/W3
// blocks [1344,2496): transpose+split W1/W2 -> [j][k]
// blocks [2496,2752): T-init — out[n,m] = T[n] = sum_d text[n,d]
__global__ __launch_bounds__(256) void prep_kernel(
    const float* __restrict__ text, const float* __restrict__ visual,
    const float* __restrict__ W1, const float* __restrict__ W2,
    const float* __restrict__ W3,
    ushort* __restrict__ th, ushort* __restrict__ tl,
    ushort* __restrict__ vh, ushort* __restrict__ vl,
    ushort* __restrict__ w3h, ushort* __restrict__ w3l,
    ushort* __restrict__ w1th, ushort* __restrict__ w1tl,
    ushort* __restrict__ w2th, ushort* __restrict__ w2tl,
    float* __restrict__ out)
{
  __shared__ float Lt[32][33];
  const int b = blockIdx.x;
  const int t = threadIdx.x;

  if (b < 1344) {
    const float* src; ushort *dh, *dl; size_t off;
    if (b < 384)      { src = text;   dh = th;  dl = tl;  off = (size_t)b * 1024; }
    else if (b < 768) { src = visual; dh = vh;  dl = vl;  off = (size_t)(b - 384) * 1024; }
    else              { src = W3;     dh = w3h; dl = w3l; off = (size_t)(b - 768) * 1024; }
    const size_t i = off + (size_t)t * 4;
    const float4 v = *(const float4*)&src[i];
    ushort4 h, l;
    splitf(v.x, h.x, l.x); splitf(v.y, h.y, l.y);
    splitf(v.z, h.z, l.z); splitf(v.w, h.w, l.w);
    *(ushort4*)&dh[i] = h;
    *(ushort4*)&dl[i] = l;
  } else if (b < 2496) {
    const int tt = b - 1344;
    const bool second = tt >= 576;
    const int tile = second ? tt - 576 : tt;
    const float* W = second ? W2 : W1;
    ushort* oh = second ? w2th : w1th;
    ushort* ol = second ? w2tl : w1tl;
    const int k0 = (tile / 24) * 32, j0 = (tile % 24) * 32;
    {
      const int k = t >> 3, j4 = (t & 7) * 4;
      const float4 v = *(const float4*)&W[(size_t)(k0 + k) * DD + j0 + j4];
      Lt[j4 + 0][k] = v.x; Lt[j4 + 1][k] = v.y;
      Lt[j4 + 2][k] = v.z; Lt[j4 + 3][k] = v.w;
    }
    __syncthreads();
    {
      const int j = t >> 3, k4 = (t & 7) * 4;
      ushort4 h, l;
      splitf(Lt[j][k4 + 0], h.x, l.x); splitf(Lt[j][k4 + 1], h.y, l.y);
      splitf(Lt[j][k4 + 2], h.z, l.z); splitf(Lt[j][k4 + 3], h.w, l.w);
      *(ushort4*)&oh[(size_t)(j0 + j) * DD + k0 + k4] = h;
      *(ushort4*)&ol[(size_t)(j0 + j) * DD + k0 + k4] = l;
    }
  } else {
    // T-init: rows n0, n0+1; out[row][:] = T[row]
    float* red = (float*)Lt;          // 258 floats needed, 1056 available
    const int u = b - 2496;
    const int n0 = u * 2;
    const int half = t >> 7;
    const int lt = t & 127;

    const float* tr = text + (size_t)(n0 + half) * DD;
    float s = 0.f;
    #pragma unroll
    for (int i = 0; i < DD / 128; ++i) s += tr[lt + i * 128];
    red[t] = s;
    __syncthreads();
    #pragma unroll
    for (int st = 64; st > 0; st >>= 1) {
      if (lt < st) red[t] += red[t + st];
      __syncthreads();
    }
    const float Tn = red[half << 7];
    float4 o; o.x = Tn; o.y = Tn; o.z = Tn; o.w = Tn;
    *(float4*)&out[(size_t)(n0 + half) * MM + lt * 4] = o;
  }
}

// ---- staged-LDS MFMA GEMM core, 32x64 tile + k0 (R6-proven) ----------------
#define BK   32
#define LROW 40            // padded LDS row stride (f16): 2-way banks, 16B-aligned
#define APL  (32 * LROW)   // one A plane (rows x LROW), in ushorts
#define BPL  (64 * LROW)   // one B plane

template <bool ALO>
__device__ __forceinline__ void gemm_core32(
    ushort* __restrict__ As, ushort* __restrict__ Bs,  // [2 buf][2 hi/lo][plane]
    const ushort* __restrict__ Ahg, const ushort* __restrict__ Alg,
    const ushort* __restrict__ Bhg, const ushort* __restrict__ Blg,
    int i0, int j0, int k0, int nsteps, f32x4* acc)
{
  const int tid = threadIdx.x;
  const int row = tid >> 2;             // 0..63 staging row (B); 0..31 for A
  const int ks8 = (tid & 3) * 8;        // 0,8,16,24 (f16)
  const bool doA = (row < 32);          // waves 0,1 stage A too (wave-uniform)
  const size_t ga = (size_t)(i0 + row) * DD + k0 + ks8;
  const size_t gb = (size_t)(j0 + row) * DD + k0 + ks8;
  const int lw = row * LROW + ks8;

  const int lane = tid & 63, wave = tid >> 6;
  const int r15 = lane & 15, quad = lane >> 4;
  const int wr = wave >> 1, wc = wave & 1;              // 2x2 wave grid
  const int fa = (wr * 16 + r15) * LROW + quad * 8;     // A frag offset
  const int fb = (wc * 32 + r15) * LROW + quad * 8;     // B frag base

  h8 pah, pal, pbh, pbl;
  if (doA) {
    pah = *(const h8*)(Ahg + ga);
    if (ALO) pal = *(const h8*)(Alg + ga);
  }
  pbh = *(const h8*)(Bhg + gb);
  pbl = *(const h8*)(Blg + gb);

  int p = 0;
  if (doA) {
    *(h8*)&As[lw] = pah;
    if (ALO) *(h8*)&As[APL + lw] = pal;
  }
  *(h8*)&Bs[lw] = pbh;
  *(h8*)&Bs[BPL + lw] = pbl;
  __syncthreads();

  for (int s = 0; s < nsteps; ++s) {
    const bool more = (s + 1 < nsteps);
    if (more) {  // issue next chunk's globals; MFMA below hides latency
      if (doA) {
        pah = *(const h8*)(Ahg + ga + (s + 1) * BK);
        if (ALO) pal = *(const h8*)(Alg + ga + (s + 1) * BK);
      }
      pbh = *(const h8*)(Bhg + gb + (s + 1) * BK);
      pbl = *(const h8*)(Blg + gb + (s + 1) * BK);
    }
    ushort* Ac = As + p * 2 * APL;
    ushort* Bc = Bs + p * 2 * BPL;
    const h8 a_h = *(const h8*)&Ac[fa];
    h8 a_l; if (ALO) a_l = *(const h8*)&Ac[APL + fa];
    h8 b_h[2], b_l[2];
    #pragma unroll
    for (int c = 0; c < 2; ++c) {
      b_h[c] = *(const h8*)&Bc[fb + c * 16 * LROW];
      b_l[c] = *(const h8*)&Bc[BPL + fb + c * 16 * LROW];
    }
    #pragma unroll
    for (int c = 0; c < 2; ++c)
      acc[c] = __builtin_amdgcn_mfma_f32_16x16x32_f16(a_h, b_h[c], acc[c], 0, 0, 0);
    #pragma unroll
    for (int c = 0; c < 2; ++c)
      acc[c] = __builtin_amdgcn_mfma_f32_16x16x32_f16(a_h, b_l[c], acc[c], 0, 0, 0);
    if (ALO) {
      #pragma unroll
      for (int c = 0; c < 2; ++c)
        acc[c] = __builtin_amdgcn_mfma_f32_16x16x32_f16(a_l, b_h[c], acc[c], 0, 0, 0);
    }
    if (more) {
      const int q = p ^ 1;
      ushort* An = As + q * 2 * APL;
      ushort* Bn = Bs + q * 2 * BPL;
      if (doA) {
        *(h8*)&An[lw] = pah;
        if (ALO) *(h8*)&An[APL + lw] = pal;
      }
      *(h8*)&Bn[lw] = pbh;
      *(h8*)&Bn[BPL + lw] = pbl;
    }
    __syncthreads();
    p ^= 1;
  }
}

// z=0: A=text@W1 -> Ah/Al(f16)  z=1: kw2t=PRE_K*text@W2  z=2: kw3v=PRE_K*visual@W3^T
// grid (DD/64, NN/32, 3) = (12, 16, 3) = 576 blocks.
__global__ __launch_bounds__(256) void mfma1_kernel(
    const ushort* __restrict__ th, const ushort* __restrict__ tl,
    const ushort* __restrict__ vh, const ushort* __restrict__ vl,
    const ushort* __restrict__ w1th, const ushort* __restrict__ w1tl,
    const ushort* __restrict__ w2th, const ushort* __restrict__ w2tl,
    const ushort* __restrict__ w3h, const ushort* __restrict__ w3l,
    ushort* __restrict__ Ah, ushort* __restrict__ Al,
    float* __restrict__ kw2t, float* __restrict__ kw3v)
{
  __shared__ ushort As[2 * 2 * APL];   // 10240 B
  __shared__ ushort Bs[2 * 2 * BPL];   // 20480 B

  const int z  = blockIdx.z;
  const int j0 = blockIdx.x * 64;
  const int i0 = blockIdx.y * 32;

  f32x4 acc[2];
  acc[0] = (f32x4){0.f, 0.f, 0.f, 0.f};
  acc[1] = (f32x4){0.f, 0.f, 0.f, 0.f};

  if (z == 0)
    gemm_core32<true >(As, Bs, th, tl, w1th, w1tl, i0, j0, 0, DD / BK, acc);
  else if (z == 1)
    gemm_core32<false>(As, Bs, th, tl, w2th, w2tl, i0, j0, 0, DD / BK, acc);
  else
    gemm_core32<false>(As, Bs, vh, vl, w3h,  w3l,  i0, j0, 0, DD / BK, acc);

  const int lane = threadIdx.x & 63, wave = threadIdx.x >> 6;
  const int r15 = lane & 15, quad = lane >> 4;
  const int wr = wave >> 1, wc = wave & 1;
  // C/D layout: col=lane&15 (B row j), row=quad*4+reg (A row i)
  if (z == 0) {
    #pragma unroll
    for (int c = 0; c < 2; ++c)
      #pragma unroll
      for (int r = 0; r < 4; ++r) {
        const size_t o = (size_t)(i0 + wr * 16 + quad * 4 + r) * DD
                       + j0 + wc * 32 + c * 16 + r15;
        splitf(acc[c][r], Ah[o], Al[o]);
      }
  } else {
    float* Out = (z == 1) ? kw2t : kw3v;
    #pragma unroll
    for (int c = 0; c < 2; ++c)
      #pragma unroll
      for (int r = 0; r < 4; ++r)
        Out[(size_t)(i0 + wr * 16 + quad * 4 + r) * DD + j0 + wc * 32 + c * 16 + r15] =
            acc[c][r] * PRE_K;
  }
}

// Q[z] = A @ visual^T over K quarter z.  Split into two launches of z-range 2
// (diagnostic): grid (8, 16, 2) x {zbase 0, 2}.
__global__ __launch_bounds__(256) void mfma2_kernel(
    const ushort* __restrict__ Ah, const ushort* __restrict__ Al,
    const ushort* __restrict__ vh, const ushort* __restrict__ vl,
    float* __restrict__ Q, int zbase)
{
  __shared__ ushort As[2 * 2 * APL];
  __shared__ ushort Bs[2 * 2 * BPL];

  const int z  = blockIdx.z + zbase;
  const int j0 = blockIdx.x * 64;
  const int i0 = blockIdx.y * 32;

  f32x4 acc[2];
  acc[0] = (f32x4){0.f, 0.f, 0.f, 0.f};
  acc[1] = (f32x4){0.f, 0.f, 0.f, 0.f};
  gemm_core32<true>(As, Bs, Ah, Al, vh, vl, i0, j0, z * (DD / 4), (DD / 4) / BK, acc);

  const int lane = threadIdx.x & 63, wave = threadIdx.x >> 6;
  const int r15 = lane & 15, quad = lane >> 4;
  const int wr = wave >> 1, wc = wave & 1;
  float* Qp = Q + (size_t)z * NN * MM;
  #pragma unroll
  for (int c = 0; c < 2; ++c)
    #pragma unroll
    for (int r = 0; r < 4; ++r)
      Qp[(size_t)(i0 + wr * 16 + quad * 4 + r) * MM + j0 + wc * 32 + c * 16 + r15] =
          acc[c][r];
}

// ---- main fused kernel (R6-proven body, FROZEN; z split across 2 launches) -
#define DCH    32
#define DRANGE 192
#define MLDW   36

__global__ __launch_bounds__(256, 4) void main_kernel(
    const float* __restrict__ text, const float* __restrict__ kw2t,
    const float* __restrict__ kw3v, const float* __restrict__ Q,
    float* __restrict__ out, int zbase)
{
  __shared__ float sbuf[2][64 * MLDW];   // 2 x 9216 B = 18432 B

  const int tid = threadIdx.x;
  const int nl = tid >> 4;
  const int ml = tid & 15;
  const int n0 = blockIdx.y * 16;
  const int m0 = blockIdx.x * 32;
  const int z  = blockIdx.z + zbase;
  const int n  = n0 + nl;
  const int mA = m0 + ml, mB = mA + 16;
  const int dbase = z * DRANGE;

  float cA = 0.f, cB = 0.f;
  #pragma unroll
  for (int zz = 0; zz < 4; ++zz) {
    const float* q = Q + (size_t)zz * NN * MM + (size_t)n * MM;
    cA += q[mA]; cB += q[mB];
  }
  cA = fast_tanh(cA); cB = fast_tanh(cB);

  float4 aA = {0.f, 0.f, 0.f, 0.f};
  float4 aB = {0.f, 0.f, 0.f, 0.f};

  // staging: 64 rows (text 0..15 | kw2t 16..31 | kw3v 32..63) x 32 cols
  const int srow = tid >> 3;              // 0..31
  const int sc   = (tid & 7) << 2;        // 0,4,...,28
  const float* g1 = (srow < 16)
      ? &text[(size_t)(n0 + srow) * DD + dbase + sc]
      : &kw2t[(size_t)(n0 + srow - 16) * DD + dbase + sc];
  const float* g3 = &kw3v[(size_t)(m0 + srow) * DD + dbase + sc];
  const int w1 = srow * MLDW + sc;          // rows 0..31 (text | kw2t)
  const int w3 = (32 + srow) * MLDW + sc;   // rows 32..63 (kw3v, 32 rows)

  // prologue: stage chunk 0 into buffer 0
  float4 r1 = *(const float4*)g1;
  float4 r3 = *(const float4*)g3;
  int p = 0;
  *(float4*)&sbuf[0][w1] = r1;
  *(float4*)&sbuf[0][w3] = r3;
  __syncthreads();

  #pragma unroll
  for (int c = 0; c < DRANGE / DCH; ++c) {   // 6 chunks
    const bool more = (c + 1 < DRANGE / DCH);
    if (more) {  // prefetch next chunk; compute below hides latency
      r1 = *(const float4*)(g1 + (c + 1) * DCH);
      r3 = *(const float4*)(g3 + (c + 1) * DCH);
    }
    const float* bp = sbuf[p];
    #pragma unroll 4
    for (int j = 0; j < DCH; j += 4) {
      const float4 tv  = *(const float4*)&bp[nl * MLDW + j];
      const float4 w2v = *(const float4*)&bp[(16 + nl) * MLDW + j];
      const float4 w3A = *(const float4*)&bp[(32 + ml) * MLDW + j];
      const float4 w3B = *(const float4*)&bp[(48 + ml) * MLDW + j];
      aA.x = fmaf(tv.x, frcp(fexp(fmaf(w3A.x, cA, w2v.x)) + 1.0f), aA.x);
      aA.y = fmaf(tv.y, frcp(fexp(fmaf(w3A.y, cA, w2v.y)) + 1.0f), aA.y);
      aA.z = fmaf(tv.z, frcp(fexp(fmaf(w3A.z, cA, w2v.z)) + 1.0f), aA.z);
      aA.w = fmaf(tv.w, frcp(fexp(fmaf(w3A.w, cA, w2v.w)) + 1.0f), aA.w);
      aB.x = fmaf(tv.x, frcp(fexp(fmaf(w3B.x, cB, w2v.x)) + 1.0f), aB.x);
      aB.y = fmaf(tv.y, frcp(fexp(fmaf(w3B.y, cB, w2v.y)) + 1.0f), aB.y);
      aB.z = fmaf(tv.z, frcp(fexp(fmaf(w3B.z, cB, w2v.z)) + 1.0f), aB.z);
      aB.w = fmaf(tv.w, frcp(fexp(fmaf(w3B.w, cB, w2v.w)) + 1.0f), aB.w);
    }
    if (more) {
      const int q = p ^ 1;
      *(float4*)&sbuf[q][w1] = r1;
      *(float4*)&sbuf[q][w3] = r3;
    }
    __syncthreads();   // single barrier per chunk
    p ^= 1;
  }

  float* op = out + (size_t)n * MM;
  unsafeAtomicAdd(&op[mA], -2.0f * ((aA.x + aA.y) + (aA.z + aA.w)));
  unsafeAtomicAdd(&op[mB], -2.0f * ((aB.x + aB.y) + (aB.z + aB.w)));
}

// ---- launcher --------------------------------------------------------------
extern "C" void kernel_launch(void* const* d_in, const int* in_sizes, int n_in,
                              void* d_out, int out_size, void* d_ws, size_t ws_size,
                              hipStream_t stream) {
  const float* text   = (const float*)d_in[0];
  const float* visual = (const float*)d_in[1];
  const float* W1     = (const float*)d_in[2];
  const float* W2     = (const float*)d_in[3];
  const float* W3     = (const float*)d_in[4];
  float* out = (float*)d_out;

  // Workspace byte layout (peak 14.25 MB, proven available):
  //   th/tl/vh/vl : f16 hi/lo of text, visual     (4 x 768 KB)
  //   w1t/w2t h,l : f16 hi/lo of W1^T,W2^T [j][k] (4 x 1.125 MB)
  //   w3 h/l      : f16 hi/lo of W3 [j][k]        (2 x 1.125 MB)
  //   Ah/Al       : f16 hi/lo of A                (2 x 768 KB)
  //   kw2t/kw3v   : fp32                          (2 x 1.5 MB)
  // Overlay (stream-serial; sources dead before overwrite):
  //   Q (4 MB) -> w1th..w2tl  (dead after mfma1; mfma2 writes Q)
  char* base = (char*)d_ws;
  ushort* th   = (ushort*)(base);
  ushort* tl   = (ushort*)(base + 786432);
  ushort* vh   = (ushort*)(base + 1572864);
  ushort* vl   = (ushort*)(base + 2359296);
  ushort* w1th = (ushort*)(base + 3145728);
  ushort* w1tl = (ushort*)(base + 4325376);
  ushort* w2th = (ushort*)(base + 5505024);
  ushort* w2tl = (ushort*)(base + 6684672);
  ushort* w3h  = (ushort*)(base + 7864320);
  ushort* w3l  = (ushort*)(base + 9043968);
  ushort* Ah   = (ushort*)(base + 10223616);
  ushort* Al   = (ushort*)(base + 11010048);
  float*  kw2t = (float*) (base + 11796480);
  float*  kw3v = (float*) (base + 13369344);
  float*  Q    = (float*) (base + 3145728);   // 4 MB over w1t/w2t

  hipLaunchKernelGGL(prep_kernel, dim3(2752), dim3(256), 0, stream,
                     text, visual, W1, W2, W3,
                     th, tl, vh, vl, w3h, w3l, w1th, w1tl, w2th, w2tl, out);
  hipLaunchKernelGGL(mfma1_kernel, dim3(DD / 64, NN / 32, 3), dim3(256), 0, stream,
                     th, tl, vh, vl, w1th, w1tl, w2th, w2tl, w3h, w3l,
                     Ah, Al, kw2t, kw3v);
  hipLaunchKernelGGL(mfma2_kernel, dim3(MM / 64, NN / 32, 2), dim3(256), 0, stream,
                     Ah, Al, vh, vl, Q, 0);
  hipLaunchKernelGGL(mfma2_kernel, dim3(MM / 64, NN / 32, 2), dim3(256), 0, stream,
                     Ah, Al, vh, vl, Q, 2);
  hipLaunchKernelGGL(main_kernel, dim3(MM / 32, NN / 16, 2), dim3(256), 0, stream,
                     text, kw2t, kw3v, Q, out, 0);
  hipLaunchKernelGGL(main_kernel, dim3(MM / 32, NN / 16, 2), dim3(256), 0, stream,
                     text, kw2t, kw3v, Q, out, 2);
}

// Round 10
// 132.615 us; speedup vs baseline: 1.0509x; 1.0509x over previous
//
#include <hip/hip_runtime.h>

// Problem dims (hard-coded in reference)
#define DD   768
#define NN   512
#define MM   512

#define PRE_K 2.88539008177792681472f   // 2*log2(e)

typedef _Float16 h8 __attribute__((ext_vector_type(8)));  // 8 f16 (4 VGPRs)
typedef __attribute__((ext_vector_type(4))) float f32x4;  // MFMA C/D

__device__ __forceinline__ float fexp(float x) { return __builtin_amdgcn_exp2f(x); }
__device__ __forceinline__ float frcp(float x) { return __builtin_amdgcn_rcpf(x); }
// tanh(x) = 1 - 2/(1 + e^{2x}); saturates correctly via exp2->inf/0 + rcp.
__device__ __forceinline__ float fast_tanh(float x) {
  return 1.0f - 2.0f * frcp(fexp(PRE_K * x) + 1.0f);
}
// Ledger: R13 keep HW trans. R17 mega-kernel catastrophic. R18 bounds(256,8)
// spills. R19(R6, BEST 131.1): main 44.8 @ occ 40 = trans floor, body FROZEN.
// R20 BK64 neutral. R21 in-GEMM convert neutral. R22(R9) MEASUREMENT: harness
// workspace re-poison fill = 42us @ 256MiB in-stream (not ours); per-dispatch
// gap ~3-4us. R23(this): associativity Q = text@(W1@visual^T): V1t joins the
// input-only GEMM stage (W1 untransposed), Q fused into main phase-1 (R3-proven
// code) at z4/2048-block occupancy where latency chains overlap (R1's failure
// was 2 blocks/CU). 4 dispatches -> 3; Q buffer (4MB W + 16MB R) deleted.

// fp32 -> f16 hi/lo split (pair covers ~21 mantissa bits)
__device__ __forceinline__ void splitf(float x, ushort& h, ushort& l) {
  const _Float16 hh = (_Float16)x;
  const _Float16 ll = (_Float16)(x - (float)hh);
  h = __builtin_bit_cast(unsigned short, hh);
  l = __builtin_bit_cast(unsigned short, ll);
}

// ---- fused prep ------------------------------------------------------------
// blocks [0,1920): straight f16 hi/lo split of text/visual/W3/W1
// blocks [1920,2496): transpose+split W2 -> [j][k]
// blocks [2496,2752): T-init — out[n,m] = T[n] = sum_d text[n,d]
__global__ __launch_bounds__(256) void prep_kernel(
    const float* __restrict__ text, const float* __restrict__ visual,
    const float* __restrict__ W1, const float* __restrict__ W2,
    const float* __restrict__ W3,
    ushort* __restrict__ th, ushort* __restrict__ tl,
    ushort* __restrict__ vh, ushort* __restrict__ vl,
    ushort* __restrict__ w3h, ushort* __restrict__ w3l,
    ushort* __restrict__ w1h, ushort* __restrict__ w1l,
    ushort* __restrict__ w2th, ushort* __restrict__ w2tl,
    float* __restrict__ out)
{
  __shared__ float Lt[32][33];
  const int b = blockIdx.x;
  const int t = threadIdx.x;

  if (b < 1920) {
    const float* src; ushort *dh, *dl; size_t off;
    if (b < 384)       { src = text;   dh = th;  dl = tl;  off = (size_t)b * 1024; }
    else if (b < 768)  { src = visual; dh = vh;  dl = vl;  off = (size_t)(b - 384) * 1024; }
    else if (b < 1344) { src = W3;     dh = w3h; dl = w3l; off = (size_t)(b - 768) * 1024; }
    else               { src = W1;     dh = w1h; dl = w1l; off = (size_t)(b - 1344) * 1024; }
    const size_t i = off + (size_t)t * 4;
    const float4 v = *(const float4*)&src[i];
    ushort4 h, l;
    splitf(v.x, h.x, l.x); splitf(v.y, h.y, l.y);
    splitf(v.z, h.z, l.z); splitf(v.w, h.w, l.w);
    *(ushort4*)&dh[i] = h;
    *(ushort4*)&dl[i] = l;
  } else if (b < 2496) {
    const int tile = b - 1920;          // 576 tiles: W2 transpose
    const int k0 = (tile / 24) * 32, j0 = (tile % 24) * 32;
    {
      const int k = t >> 3, j4 = (t & 7) * 4;
      const float4 v = *(const float4*)&W2[(size_t)(k0 + k) * DD + j0 + j4];
      Lt[j4 + 0][k] = v.x; Lt[j4 + 1][k] = v.y;
      Lt[j4 + 2][k] = v.z; Lt[j4 + 3][k] = v.w;
    }
    __syncthreads();
    {
      const int j = t >> 3, k4 = (t & 7) * 4;
      ushort4 h, l;
      splitf(Lt[j][k4 + 0], h.x, l.x); splitf(Lt[j][k4 + 1], h.y, l.y);
      splitf(Lt[j][k4 + 2], h.z, l.z); splitf(Lt[j][k4 + 3], h.w, l.w);
      *(ushort4*)&w2th[(size_t)(j0 + j) * DD + k0 + k4] = h;
      *(ushort4*)&w2tl[(size_t)(j0 + j) * DD + k0 + k4] = l;
    }
  } else {
    // T-init: rows n0, n0+1; out[row][:] = T[row]
    float* red = (float*)Lt;          // 258 floats needed, 1056 available
    const int u = b - 2496;
    const int n0 = u * 2;
    const int half = t >> 7;
    const int lt = t & 127;

    const float* tr = text + (size_t)(n0 + half) * DD;
    float s = 0.f;
    #pragma unroll
    for (int i = 0; i < DD / 128; ++i) s += tr[lt + i * 128];
    red[t] = s;
    __syncthreads();
    #pragma unroll
    for (int st = 64; st > 0; st >>= 1) {
      if (lt < st) red[t] += red[t + st];
      __syncthreads();
    }
    const float Tn = red[half << 7];
    float4 o; o.x = Tn; o.y = Tn; o.z = Tn; o.w = Tn;
    *(float4*)&out[(size_t)(n0 + half) * MM + lt * 4] = o;
  }
}

// ---- staged-LDS MFMA GEMM core, 32x64 tile + k0 (R6-proven) ----------------
#define BK   32
#define LROW 40            // padded LDS row stride (f16): 2-way banks, 16B-aligned
#define APL  (32 * LROW)   // one A plane (rows x LROW), in ushorts
#define BPL  (64 * LROW)   // one B plane

template <bool ALO>
__device__ __forceinline__ void gemm_core32(
    ushort* __restrict__ As, ushort* __restrict__ Bs,  // [2 buf][2 hi/lo][plane]
    const ushort* __restrict__ Ahg, const ushort* __restrict__ Alg,
    const ushort* __restrict__ Bhg, const ushort* __restrict__ Blg,
    int i0, int j0, int k0, int nsteps, f32x4* acc)
{
  const int tid = threadIdx.x;
  const int row = tid >> 2;             // 0..63 staging row (B); 0..31 for A
  const int ks8 = (tid & 3) * 8;        // 0,8,16,24 (f16)
  const bool doA = (row < 32);          // waves 0,1 stage A too (wave-uniform)
  const size_t ga = (size_t)(i0 + row) * DD + k0 + ks8;
  const size_t gb = (size_t)(j0 + row) * DD + k0 + ks8;
  const int lw = row * LROW + ks8;

  const int lane = tid & 63, wave = tid >> 6;
  const int r15 = lane & 15, quad = lane >> 4;
  const int wr = wave >> 1, wc = wave & 1;              // 2x2 wave grid
  const int fa = (wr * 16 + r15) * LROW + quad * 8;     // A frag offset
  const int fb = (wc * 32 + r15) * LROW + quad * 8;     // B frag base

  h8 pah, pal, pbh, pbl;
  if (doA) {
    pah = *(const h8*)(Ahg + ga);
    if (ALO) pal = *(const h8*)(Alg + ga);
  }
  pbh = *(const h8*)(Bhg + gb);
  pbl = *(const h8*)(Blg + gb);

  int p = 0;
  if (doA) {
    *(h8*)&As[lw] = pah;
    if (ALO) *(h8*)&As[APL + lw] = pal;
  }
  *(h8*)&Bs[lw] = pbh;
  *(h8*)&Bs[BPL + lw] = pbl;
  __syncthreads();

  for (int s = 0; s < nsteps; ++s) {
    const bool more = (s + 1 < nsteps);
    if (more) {  // issue next chunk's globals; MFMA below hides latency
      if (doA) {
        pah = *(const h8*)(Ahg + ga + (s + 1) * BK);
        if (ALO) pal = *(const h8*)(Alg + ga + (s + 1) * BK);
      }
      pbh = *(const h8*)(Bhg + gb + (s + 1) * BK);
      pbl = *(const h8*)(Blg + gb + (s + 1) * BK);
    }
    ushort* Ac = As + p * 2 * APL;
    ushort* Bc = Bs + p * 2 * BPL;
    const h8 a_h = *(const h8*)&Ac[fa];
    h8 a_l; if (ALO) a_l = *(const h8*)&Ac[APL + fa];
    h8 b_h[2], b_l[2];
    #pragma unroll
    for (int c = 0; c < 2; ++c) {
      b_h[c] = *(const h8*)&Bc[fb + c * 16 * LROW];
      b_l[c] = *(const h8*)&Bc[BPL + fb + c * 16 * LROW];
    }
    #pragma unroll
    for (int c = 0; c < 2; ++c)
      acc[c] = __builtin_amdgcn_mfma_f32_16x16x32_f16(a_h, b_h[c], acc[c], 0, 0, 0);
    #pragma unroll
    for (int c = 0; c < 2; ++c)
      acc[c] = __builtin_amdgcn_mfma_f32_16x16x32_f16(a_h, b_l[c], acc[c], 0, 0, 0);
    if (ALO) {
      #pragma unroll
      for (int c = 0; c < 2; ++c)
        acc[c] = __builtin_amdgcn_mfma_f32_16x16x32_f16(a_l, b_h[c], acc[c], 0, 0, 0);
    }
    if (more) {
      const int q = p ^ 1;
      ushort* An = As + q * 2 * APL;
      ushort* Bn = Bs + q * 2 * BPL;
      if (doA) {
        *(h8*)&An[lw] = pah;
        if (ALO) *(h8*)&An[APL + lw] = pal;
      }
      *(h8*)&Bn[lw] = pbh;
      *(h8*)&Bn[BPL + lw] = pbl;
    }
    __syncthreads();
    p ^= 1;
  }
}

// One uniform GEMM stage, all from inputs (no inter-GEMM dependency):
// z=0: V1t[m][d] = sum_j visual[m,j]*W1[d,j]  -> f16 split V1th/V1tl (ALO)
// z=1: kw2t = PRE_K * text@W2      (B = W2^T via w2t pair)
// z=2: kw3v = PRE_K * visual@W3^T  (B = W3 rows)
// grid (DD/64, NN/32, 3) = (12, 16, 3) = 576 blocks.
__global__ __launch_bounds__(256) void mfma1_kernel(
    const ushort* __restrict__ th, const ushort* __restrict__ tl,
    const ushort* __restrict__ vh, const ushort* __restrict__ vl,
    const ushort* __restrict__ w1h, const ushort* __restrict__ w1l,
    const ushort* __restrict__ w2th, const ushort* __restrict__ w2tl,
    const ushort* __restrict__ w3h, const ushort* __restrict__ w3l,
    ushort* __restrict__ V1th, ushort* __restrict__ V1tl,
    float* __restrict__ kw2t, float* __restrict__ kw3v)
{
  __shared__ ushort As[2 * 2 * APL];   // 10240 B
  __shared__ ushort Bs[2 * 2 * BPL];   // 20480 B

  const int z  = blockIdx.z;
  const int j0 = blockIdx.x * 64;
  const int i0 = blockIdx.y * 32;

  f32x4 acc[2];
  acc[0] = (f32x4){0.f, 0.f, 0.f, 0.f};
  acc[1] = (f32x4){0.f, 0.f, 0.f, 0.f};

  if (z == 0)
    gemm_core32<true >(As, Bs, vh, vl, w1h, w1l,  i0, j0, 0, DD / BK, acc);
  else if (z == 1)
    gemm_core32<false>(As, Bs, th, tl, w2th, w2tl, i0, j0, 0, DD / BK, acc);
  else
    gemm_core32<false>(As, Bs, vh, vl, w3h, w3l,  i0, j0, 0, DD / BK, acc);

  const int lane = threadIdx.x & 63, wave = threadIdx.x >> 6;
  const int r15 = lane & 15, quad = lane >> 4;
  const int wr = wave >> 1, wc = wave & 1;
  // C/D layout: col=lane&15 (B row j), row=quad*4+reg (A row i)
  if (z == 0) {
    #pragma unroll
    for (int c = 0; c < 2; ++c)
      #pragma unroll
      for (int r = 0; r < 4; ++r) {
        const size_t o = (size_t)(i0 + wr * 16 + quad * 4 + r) * DD
                       + j0 + wc * 32 + c * 16 + r15;
        splitf(acc[c][r], V1th[o], V1tl[o]);
      }
  } else {
    float* Out = (z == 1) ? kw2t : kw3v;
    #pragma unroll
    for (int c = 0; c < 2; ++c)
      #pragma unroll
      for (int r = 0; r < 4; ++r)
        Out[(size_t)(i0 + wr * 16 + quad * 4 + r) * DD + j0 + wc * 32 + c * 16 + r15] =
            acc[c][r] * PRE_K;
  }
}

// ---- main fused kernel (R6 phase-2 FROZEN + R3-proven phase-1) -------------
// Phase 1: Qtile[16][32] = (th,tl) @ (V1th,V1tl)^T-rows, K split across the
// 4 waves (wave w = K-quarter w); identical in every z-replica -> same cA/cB.
// Phase 2: R6 body (DCH 32, z4, atomics). grid (16, 32, 4) = 2048 blocks.
#define DCH    32
#define DRANGE 192
#define MLDW   36

__global__ __launch_bounds__(256, 4) void main_kernel(
    const float* __restrict__ text, const float* __restrict__ kw2t,
    const float* __restrict__ kw3v,
    const ushort* __restrict__ th, const ushort* __restrict__ tl,
    const ushort* __restrict__ V1th, const ushort* __restrict__ V1tl,
    float* __restrict__ out)
{
  __shared__ float sbuf[2][64 * MLDW];   // 18432 B; phase-1 Qs aliases sbuf[0]

  const int tid = threadIdx.x;
  const int nl = tid >> 4;
  const int ml = tid & 15;
  const int n0 = blockIdx.y * 16;
  const int m0 = blockIdx.x * 32;
  const int z  = blockIdx.z;
  const int lane = tid & 63, wave = tid >> 6;
  const int r15 = lane & 15, quad = lane >> 4;

  // ---- phase 1: Q tile (16x32) via MFMA, K-quarter per wave (R3-proven)
  const size_t aoff  = (size_t)(n0 + r15) * DD + wave * (DD / 4) + quad * 8;
  const size_t b0off = (size_t)(m0 + r15) * DD + wave * (DD / 4) + quad * 8;
  const size_t b1off = (size_t)(m0 + 16 + r15) * DD + wave * (DD / 4) + quad * 8;
  const ushort* Ap  = th + aoff;
  const ushort* Alp = tl + aoff;
  const ushort* B0h = V1th + b0off;
  const ushort* B0l = V1tl + b0off;
  const ushort* B1h = V1th + b1off;
  const ushort* B1l = V1tl + b1off;

  f32x4 q0 = {0.f, 0.f, 0.f, 0.f}, q1 = {0.f, 0.f, 0.f, 0.f};
  h8 cah  = *(const h8*)Ap;
  h8 cal  = *(const h8*)Alp;
  h8 cb0h = *(const h8*)B0h;
  h8 cb0l = *(const h8*)B0l;
  h8 cb1h = *(const h8*)B1h;
  h8 cb1l = *(const h8*)B1l;
  #pragma unroll
  for (int s = 0; s < (DD / 4) / BK; ++s) {   // 6 steps
    h8 nah, nal, nb0h, nb0l, nb1h, nb1l;
    const bool more = (s + 1 < (DD / 4) / BK);
    if (more) {
      nah  = *(const h8*)(Ap  + (s + 1) * BK);
      nal  = *(const h8*)(Alp + (s + 1) * BK);
      nb0h = *(const h8*)(B0h + (s + 1) * BK);
      nb0l = *(const h8*)(B0l + (s + 1) * BK);
      nb1h = *(const h8*)(B1h + (s + 1) * BK);
      nb1l = *(const h8*)(B1l + (s + 1) * BK);
    }
    // per-acc product order hh, hl, lh (proven numerics)
    q0 = __builtin_amdgcn_mfma_f32_16x16x32_f16(cah, cb0h, q0, 0, 0, 0);
    q1 = __builtin_amdgcn_mfma_f32_16x16x32_f16(cah, cb1h, q1, 0, 0, 0);
    q0 = __builtin_amdgcn_mfma_f32_16x16x32_f16(cah, cb0l, q0, 0, 0, 0);
    q1 = __builtin_amdgcn_mfma_f32_16x16x32_f16(cah, cb1l, q1, 0, 0, 0);
    q0 = __builtin_amdgcn_mfma_f32_16x16x32_f16(cal, cb0h, q0, 0, 0, 0);
    q1 = __builtin_amdgcn_mfma_f32_16x16x32_f16(cal, cb1h, q1, 0, 0, 0);
    if (more) { cah = nah; cal = nal; cb0h = nb0h; cb0l = nb0l; cb1h = nb1h; cb1l = nb1l; }
  }

  float (*Qs)[16][33] = (float (*)[16][33])(&sbuf[0][0]);   // 8448 B alias, padded
  #pragma unroll
  for (int r = 0; r < 4; ++r) {
    Qs[wave][quad * 4 + r][r15]      = q0[r];
    Qs[wave][quad * 4 + r][16 + r15] = q1[r];
  }
  __syncthreads();
  float sA = Qs[0][nl][ml];
  sA += Qs[1][nl][ml]; sA += Qs[2][nl][ml]; sA += Qs[3][nl][ml];
  float sB = Qs[0][nl][ml + 16];
  sB += Qs[1][nl][ml + 16]; sB += Qs[2][nl][ml + 16]; sB += Qs[3][nl][ml + 16];
  const float cA = fast_tanh(sA);
  const float cB = fast_tanh(sB);
  __syncthreads();   // Qs dead; sbuf reused by phase 2

  // ---- phase 2: R6-frozen transcendental loop over this z's d-range
  const int n  = n0 + nl;
  const int mA = m0 + ml, mB = mA + 16;
  const int dbase = z * DRANGE;

  float4 aA = {0.f, 0.f, 0.f, 0.f};
  float4 aB = {0.f, 0.f, 0.f, 0.f};

  // staging: 64 rows (text 0..15 | kw2t 16..31 | kw3v 32..63) x 32 cols
  const int srow = tid >> 3;              // 0..31
  const int sc   = (tid & 7) << 2;        // 0,4,...,28
  const float* g1 = (srow < 16)
      ? &text[(size_t)(n0 + srow) * DD + dbase + sc]
      : &kw2t[(size_t)(n0 + srow - 16) * DD + dbase + sc];
  const float* g3 = &kw3v[(size_t)(m0 + srow) * DD + dbase + sc];
  const int w1 = srow * MLDW + sc;          // rows 0..31 (text | kw2t)
  const int w3 = (32 + srow) * MLDW + sc;   // rows 32..63 (kw3v, 32 rows)

  // prologue: stage chunk 0 into buffer 0
  float4 r1 = *(const float4*)g1;
  float4 r3 = *(const float4*)g3;
  int p = 0;
  *(float4*)&sbuf[0][w1] = r1;
  *(float4*)&sbuf[0][w3] = r3;
  __syncthreads();

  #pragma unroll
  for (int c = 0; c < DRANGE / DCH; ++c) {   // 6 chunks
    const bool more = (c + 1 < DRANGE / DCH);
    if (more) {  // prefetch next chunk; compute below hides latency
      r1 = *(const float4*)(g1 + (c + 1) * DCH);
      r3 = *(const float4*)(g3 + (c + 1) * DCH);
    }
    const float* bp = sbuf[p];
    #pragma unroll 4
    for (int j = 0; j < DCH; j += 4) {
      const float4 tv  = *(const float4*)&bp[nl * MLDW + j];
      const float4 w2v = *(const float4*)&bp[(16 + nl) * MLDW + j];
      const float4 w3A = *(const float4*)&bp[(32 + ml) * MLDW + j];
      const float4 w3B = *(const float4*)&bp[(48 + ml) * MLDW + j];
      aA.x = fmaf(tv.x, frcp(fexp(fmaf(w3A.x, cA, w2v.x)) + 1.0f), aA.x);
      aA.y = fmaf(tv.y, frcp(fexp(fmaf(w3A.y, cA, w2v.y)) + 1.0f), aA.y);
      aA.z = fmaf(tv.z, frcp(fexp(fmaf(w3A.z, cA, w2v.z)) + 1.0f), aA.z);
      aA.w = fmaf(tv.w, frcp(fexp(fmaf(w3A.w, cA, w2v.w)) + 1.0f), aA.w);
      aB.x = fmaf(tv.x, frcp(fexp(fmaf(w3B.x, cB, w2v.x)) + 1.0f), aB.x);
      aB.y = fmaf(tv.y, frcp(fexp(fmaf(w3B.y, cB, w2v.y)) + 1.0f), aB.y);
      aB.z = fmaf(tv.z, frcp(fexp(fmaf(w3B.z, cB, w2v.z)) + 1.0f), aB.z);
      aB.w = fmaf(tv.w, frcp(fexp(fmaf(w3B.w, cB, w2v.w)) + 1.0f), aB.w);
    }
    if (more) {
      const int q = p ^ 1;
      *(float4*)&sbuf[q][w1] = r1;
      *(float4*)&sbuf[q][w3] = r3;
    }
    __syncthreads();   // single barrier per chunk
    p ^= 1;
  }

  float* op = out + (size_t)n * MM;
  unsafeAtomicAdd(&op[mA], -2.0f * ((aA.x + aA.y) + (aA.z + aA.w)));
  unsafeAtomicAdd(&op[mB], -2.0f * ((aB.x + aB.y) + (aB.z + aB.w)));
}

// ---- launcher --------------------------------------------------------------
extern "C" void kernel_launch(void* const* d_in, const int* in_sizes, int n_in,
                              void* d_out, int out_size, void* d_ws, size_t ws_size,
                              hipStream_t stream) {
  const float* text   = (const float*)d_in[0];
  const float* visual = (const float*)d_in[1];
  const float* W1     = (const float*)d_in[2];
  const float* W2     = (const float*)d_in[3];
  const float* W3     = (const float*)d_in[4];
  float* out = (float*)d_out;

  // Workspace byte layout (14.25 MB, proven available):
  //   th/tl/vh/vl   : f16 hi/lo of text, visual   (4 x 768 KB)
  //   w1 h/l        : f16 hi/lo of W1 [d][j]      (2 x 1.125 MB, untransposed)
  //   w2t h/l       : f16 hi/lo of W2^T [j][k]    (2 x 1.125 MB)
  //   w3 h/l        : f16 hi/lo of W3 [j][k]      (2 x 1.125 MB)
  //   V1th/V1tl     : f16 hi/lo of V1t [m][d]     (2 x 768 KB)
  //   kw2t/kw3v     : fp32                        (2 x 1.5 MB)
  char* base = (char*)d_ws;
  ushort* th   = (ushort*)(base);
  ushort* tl   = (ushort*)(base + 786432);
  ushort* vh   = (ushort*)(base + 1572864);
  ushort* vl   = (ushort*)(base + 2359296);
  ushort* w1h  = (ushort*)(base + 3145728);
  ushort* w1l  = (ushort*)(base + 4325376);
  ushort* w2th = (ushort*)(base + 5505024);
  ushort* w2tl = (ushort*)(base + 6684672);
  ushort* w3h  = (ushort*)(base + 7864320);
  ushort* w3l  = (ushort*)(base + 9043968);
  ushort* V1th = (ushort*)(base + 10223616);
  ushort* V1tl = (ushort*)(base + 11010048);
  float*  kw2t = (float*) (base + 11796480);
  float*  kw3v = (float*) (base + 13369344);

  hipLaunchKernelGGL(prep_kernel, dim3(2752), dim3(256), 0, stream,
                     text, visual, W1, W2, W3,
                     th, tl, vh, vl, w3h, w3l, w1h, w1l, w2th, w2tl, out);
  hipLaunchKernelGGL(mfma1_kernel, dim3(DD / 64, NN / 32, 3), dim3(256), 0, stream,
                     th, tl, vh, vl, w1h, w1l, w2th, w2tl, w3h, w3l,
                     V1th, V1tl, kw2t, kw3v);
  hipLaunchKernelGGL(main_kernel, dim3(MM / 32, NN / 16, 4), dim3(256), 0, stream,
                     text, kw2t, kw3v, th, tl, V1th, V1tl, out);
}

// Round 11
// 131.619 us; speedup vs baseline: 1.0589x; 1.0076x over previous
//
#include <hip/hip_runtime.h>

// Problem dims (hard-coded in reference)
#define DD   768
#define NN   512
#define MM   512

#define PRE_K 2.88539008177792681472f   // 2*log2(e)

typedef _Float16 h8 __attribute__((ext_vector_type(8)));  // 8 f16 (4 VGPRs)
typedef __attribute__((ext_vector_type(4))) float f32x4;  // MFMA C/D

__device__ __forceinline__ float fexp(float x) { return __builtin_amdgcn_exp2f(x); }
__device__ __forceinline__ float frcp(float x) { return __builtin_amdgcn_rcpf(x); }
// tanh(x) = 1 - 2/(1 + e^{2x}); saturates correctly via exp2->inf/0 + rcp.
__device__ __forceinline__ float fast_tanh(float x) {
  return 1.0f - 2.0f * frcp(fexp(PRE_K * x) + 1.0f);
}
// Ledger: R13 keep HW trans. R17 mega-kernel catastrophic. R18 bounds(256,8)
// spills. R19(R6, 131.1): main 44.8 @ occ 40 = trans floor. R20 BK64 neutral.
// R21 in-GEMM convert neutral. R22(R9): harness re-poison fill = 42us (not
// ours); per-dispatch gap ~3-4us. R23(R10, 132.6): associativity V1t rewrite,
// Q fused into main; phase-1 premium measured = 3.6us/replica (x4 = +14.3 on
// main) vs fixed support saving 12.8. R24(this): same build, z4->z2 (DRANGE
// 384): phase-1 premium halves to +7.2, support saving kept -> predict ~125.

// fp32 -> f16 hi/lo split (pair covers ~21 mantissa bits)
__device__ __forceinline__ void splitf(float x, ushort& h, ushort& l) {
  const _Float16 hh = (_Float16)x;
  const _Float16 ll = (_Float16)(x - (float)hh);
  h = __builtin_bit_cast(unsigned short, hh);
  l = __builtin_bit_cast(unsigned short, ll);
}

// ---- fused prep ------------------------------------------------------------
// blocks [0,1920): straight f16 hi/lo split of text/visual/W3/W1
// blocks [1920,2496): transpose+split W2 -> [j][k]
// blocks [2496,2752): T-init — out[n,m] = T[n] = sum_d text[n,d]
__global__ __launch_bounds__(256) void prep_kernel(
    const float* __restrict__ text, const float* __restrict__ visual,
    const float* __restrict__ W1, const float* __restrict__ W2,
    const float* __restrict__ W3,
    ushort* __restrict__ th, ushort* __restrict__ tl,
    ushort* __restrict__ vh, ushort* __restrict__ vl,
    ushort* __restrict__ w3h, ushort* __restrict__ w3l,
    ushort* __restrict__ w1h, ushort* __restrict__ w1l,
    ushort* __restrict__ w2th, ushort* __restrict__ w2tl,
    float* __restrict__ out)
{
  __shared__ float Lt[32][33];
  const int b = blockIdx.x;
  const int t = threadIdx.x;

  if (b < 1920) {
    const float* src; ushort *dh, *dl; size_t off;
    if (b < 384)       { src = text;   dh = th;  dl = tl;  off = (size_t)b * 1024; }
    else if (b < 768)  { src = visual; dh = vh;  dl = vl;  off = (size_t)(b - 384) * 1024; }
    else if (b < 1344) { src = W3;     dh = w3h; dl = w3l; off = (size_t)(b - 768) * 1024; }
    else               { src = W1;     dh = w1h; dl = w1l; off = (size_t)(b - 1344) * 1024; }
    const size_t i = off + (size_t)t * 4;
    const float4 v = *(const float4*)&src[i];
    ushort4 h, l;
    splitf(v.x, h.x, l.x); splitf(v.y, h.y, l.y);
    splitf(v.z, h.z, l.z); splitf(v.w, h.w, l.w);
    *(ushort4*)&dh[i] = h;
    *(ushort4*)&dl[i] = l;
  } else if (b < 2496) {
    const int tile = b - 1920;          // 576 tiles: W2 transpose
    const int k0 = (tile / 24) * 32, j0 = (tile % 24) * 32;
    {
      const int k = t >> 3, j4 = (t & 7) * 4;
      const float4 v = *(const float4*)&W2[(size_t)(k0 + k) * DD + j0 + j4];
      Lt[j4 + 0][k] = v.x; Lt[j4 + 1][k] = v.y;
      Lt[j4 + 2][k] = v.z; Lt[j4 + 3][k] = v.w;
    }
    __syncthreads();
    {
      const int j = t >> 3, k4 = (t & 7) * 4;
      ushort4 h, l;
      splitf(Lt[j][k4 + 0], h.x, l.x); splitf(Lt[j][k4 + 1], h.y, l.y);
      splitf(Lt[j][k4 + 2], h.z, l.z); splitf(Lt[j][k4 + 3], h.w, l.w);
      *(ushort4*)&w2th[(size_t)(j0 + j) * DD + k0 + k4] = h;
      *(ushort4*)&w2tl[(size_t)(j0 + j) * DD + k0 + k4] = l;
    }
  } else {
    // T-init: rows n0, n0+1; out[row][:] = T[row]
    float* red = (float*)Lt;          // 258 floats needed, 1056 available
    const int u = b - 2496;
    const int n0 = u * 2;
    const int half = t >> 7;
    const int lt = t & 127;

    const float* tr = text + (size_t)(n0 + half) * DD;
    float s = 0.f;
    #pragma unroll
    for (int i = 0; i < DD / 128; ++i) s += tr[lt + i * 128];
    red[t] = s;
    __syncthreads();
    #pragma unroll
    for (int st = 64; st > 0; st >>= 1) {
      if (lt < st) red[t] += red[t + st];
      __syncthreads();
    }
    const float Tn = red[half << 7];
    float4 o; o.x = Tn; o.y = Tn; o.z = Tn; o.w = Tn;
    *(float4*)&out[(size_t)(n0 + half) * MM + lt * 4] = o;
  }
}

// ---- staged-LDS MFMA GEMM core, 32x64 tile + k0 (R6-proven) ----------------
#define BK   32
#define LROW 40            // padded LDS row stride (f16): 2-way banks, 16B-aligned
#define APL  (32 * LROW)   // one A plane (rows x LROW), in ushorts
#define BPL  (64 * LROW)   // one B plane

template <bool ALO>
__device__ __forceinline__ void gemm_core32(
    ushort* __restrict__ As, ushort* __restrict__ Bs,  // [2 buf][2 hi/lo][plane]
    const ushort* __restrict__ Ahg, const ushort* __restrict__ Alg,
    const ushort* __restrict__ Bhg, const ushort* __restrict__ Blg,
    int i0, int j0, int k0, int nsteps, f32x4* acc)
{
  const int tid = threadIdx.x;
  const int row = tid >> 2;             // 0..63 staging row (B); 0..31 for A
  const int ks8 = (tid & 3) * 8;        // 0,8,16,24 (f16)
  const bool doA = (row < 32);          // waves 0,1 stage A too (wave-uniform)
  const size_t ga = (size_t)(i0 + row) * DD + k0 + ks8;
  const size_t gb = (size_t)(j0 + row) * DD + k0 + ks8;
  const int lw = row * LROW + ks8;

  const int lane = tid & 63, wave = tid >> 6;
  const int r15 = lane & 15, quad = lane >> 4;
  const int wr = wave >> 1, wc = wave & 1;              // 2x2 wave grid
  const int fa = (wr * 16 + r15) * LROW + quad * 8;     // A frag offset
  const int fb = (wc * 32 + r15) * LROW + quad * 8;     // B frag base

  h8 pah, pal, pbh, pbl;
  if (doA) {
    pah = *(const h8*)(Ahg + ga);
    if (ALO) pal = *(const h8*)(Alg + ga);
  }
  pbh = *(const h8*)(Bhg + gb);
  pbl = *(const h8*)(Blg + gb);

  int p = 0;
  if (doA) {
    *(h8*)&As[lw] = pah;
    if (ALO) *(h8*)&As[APL + lw] = pal;
  }
  *(h8*)&Bs[lw] = pbh;
  *(h8*)&Bs[BPL + lw] = pbl;
  __syncthreads();

  for (int s = 0; s < nsteps; ++s) {
    const bool more = (s + 1 < nsteps);
    if (more) {  // issue next chunk's globals; MFMA below hides latency
      if (doA) {
        pah = *(const h8*)(Ahg + ga + (s + 1) * BK);
        if (ALO) pal = *(const h8*)(Alg + ga + (s + 1) * BK);
      }
      pbh = *(const h8*)(Bhg + gb + (s + 1) * BK);
      pbl = *(const h8*)(Blg + gb + (s + 1) * BK);
    }
    ushort* Ac = As + p * 2 * APL;
    ushort* Bc = Bs + p * 2 * BPL;
    const h8 a_h = *(const h8*)&Ac[fa];
    h8 a_l; if (ALO) a_l = *(const h8*)&Ac[APL + fa];
    h8 b_h[2], b_l[2];
    #pragma unroll
    for (int c = 0; c < 2; ++c) {
      b_h[c] = *(const h8*)&Bc[fb + c * 16 * LROW];
      b_l[c] = *(const h8*)&Bc[BPL + fb + c * 16 * LROW];
    }
    #pragma unroll
    for (int c = 0; c < 2; ++c)
      acc[c] = __builtin_amdgcn_mfma_f32_16x16x32_f16(a_h, b_h[c], acc[c], 0, 0, 0);
    #pragma unroll
    for (int c = 0; c < 2; ++c)
      acc[c] = __builtin_amdgcn_mfma_f32_16x16x32_f16(a_h, b_l[c], acc[c], 0, 0, 0);
    if (ALO) {
      #pragma unroll
      for (int c = 0; c < 2; ++c)
        acc[c] = __builtin_amdgcn_mfma_f32_16x16x32_f16(a_l, b_h[c], acc[c], 0, 0, 0);
    }
    if (more) {
      const int q = p ^ 1;
      ushort* An = As + q * 2 * APL;
      ushort* Bn = Bs + q * 2 * BPL;
      if (doA) {
        *(h8*)&An[lw] = pah;
        if (ALO) *(h8*)&An[APL + lw] = pal;
      }
      *(h8*)&Bn[lw] = pbh;
      *(h8*)&Bn[BPL + lw] = pbl;
    }
    __syncthreads();
    p ^= 1;
  }
}

// One uniform GEMM stage, all from inputs (no inter-GEMM dependency):
// z=0: V1t[m][d] = sum_j visual[m,j]*W1[d,j]  -> f16 split V1th/V1tl (ALO)
// z=1: kw2t = PRE_K * text@W2      (B = W2^T via w2t pair)
// z=2: kw3v = PRE_K * visual@W3^T  (B = W3 rows)
// grid (DD/64, NN/32, 3) = (12, 16, 3) = 576 blocks.
__global__ __launch_bounds__(256) void mfma1_kernel(
    const ushort* __restrict__ th, const ushort* __restrict__ tl,
    const ushort* __restrict__ vh, const ushort* __restrict__ vl,
    const ushort* __restrict__ w1h, const ushort* __restrict__ w1l,
    const ushort* __restrict__ w2th, const ushort* __restrict__ w2tl,
    const ushort* __restrict__ w3h, const ushort* __restrict__ w3l,
    ushort* __restrict__ V1th, ushort* __restrict__ V1tl,
    float* __restrict__ kw2t, float* __restrict__ kw3v)
{
  __shared__ ushort As[2 * 2 * APL];   // 10240 B
  __shared__ ushort Bs[2 * 2 * BPL];   // 20480 B

  const int z  = blockIdx.z;
  const int j0 = blockIdx.x * 64;
  const int i0 = blockIdx.y * 32;

  f32x4 acc[2];
  acc[0] = (f32x4){0.f, 0.f, 0.f, 0.f};
  acc[1] = (f32x4){0.f, 0.f, 0.f, 0.f};

  if (z == 0)
    gemm_core32<true >(As, Bs, vh, vl, w1h, w1l,  i0, j0, 0, DD / BK, acc);
  else if (z == 1)
    gemm_core32<false>(As, Bs, th, tl, w2th, w2tl, i0, j0, 0, DD / BK, acc);
  else
    gemm_core32<false>(As, Bs, vh, vl, w3h, w3l,  i0, j0, 0, DD / BK, acc);

  const int lane = threadIdx.x & 63, wave = threadIdx.x >> 6;
  const int r15 = lane & 15, quad = lane >> 4;
  const int wr = wave >> 1, wc = wave & 1;
  // C/D layout: col=lane&15 (B row j), row=quad*4+reg (A row i)
  if (z == 0) {
    #pragma unroll
    for (int c = 0; c < 2; ++c)
      #pragma unroll
      for (int r = 0; r < 4; ++r) {
        const size_t o = (size_t)(i0 + wr * 16 + quad * 4 + r) * DD
                       + j0 + wc * 32 + c * 16 + r15;
        splitf(acc[c][r], V1th[o], V1tl[o]);
      }
  } else {
    float* Out = (z == 1) ? kw2t : kw3v;
    #pragma unroll
    for (int c = 0; c < 2; ++c)
      #pragma unroll
      for (int r = 0; r < 4; ++r)
        Out[(size_t)(i0 + wr * 16 + quad * 4 + r) * DD + j0 + wc * 32 + c * 16 + r15] =
            acc[c][r] * PRE_K;
  }
}

// ---- main fused kernel (R10 body, z4 -> z2) --------------------------------
// Phase 1: Qtile[16][32] = (th,tl) @ (V1th,V1tl), K-quarter per wave (proven
// R10); identical in both z-replicas -> same cA/cB. Phase 2: R6-frozen loop,
// DRANGE 384 (12 chunks). grid (16, 32, 2) = 1024 blocks = 4/CU.
#define DCH    32
#define DRANGE 384
#define MLDW   36

__global__ __launch_bounds__(256, 4) void main_kernel(
    const float* __restrict__ text, const float* __restrict__ kw2t,
    const float* __restrict__ kw3v,
    const ushort* __restrict__ th, const ushort* __restrict__ tl,
    const ushort* __restrict__ V1th, const ushort* __restrict__ V1tl,
    float* __restrict__ out)
{
  __shared__ float sbuf[2][64 * MLDW];   // 18432 B; phase-1 Qs aliases sbuf[0]

  const int tid = threadIdx.x;
  const int nl = tid >> 4;
  const int ml = tid & 15;
  const int n0 = blockIdx.y * 16;
  const int m0 = blockIdx.x * 32;
  const int z  = blockIdx.z;
  const int lane = tid & 63, wave = tid >> 6;
  const int r15 = lane & 15, quad = lane >> 4;

  // ---- phase 1: Q tile (16x32) via MFMA, K-quarter per wave (R10-proven)
  const size_t aoff  = (size_t)(n0 + r15) * DD + wave * (DD / 4) + quad * 8;
  const size_t b0off = (size_t)(m0 + r15) * DD + wave * (DD / 4) + quad * 8;
  const size_t b1off = (size_t)(m0 + 16 + r15) * DD + wave * (DD / 4) + quad * 8;
  const ushort* Ap  = th + aoff;
  const ushort* Alp = tl + aoff;
  const ushort* B0h = V1th + b0off;
  const ushort* B0l = V1tl + b0off;
  const ushort* B1h = V1th + b1off;
  const ushort* B1l = V1tl + b1off;

  f32x4 q0 = {0.f, 0.f, 0.f, 0.f}, q1 = {0.f, 0.f, 0.f, 0.f};
  h8 cah  = *(const h8*)Ap;
  h8 cal  = *(const h8*)Alp;
  h8 cb0h = *(const h8*)B0h;
  h8 cb0l = *(const h8*)B0l;
  h8 cb1h = *(const h8*)B1h;
  h8 cb1l = *(const h8*)B1l;
  #pragma unroll
  for (int s = 0; s < (DD / 4) / BK; ++s) {   // 6 steps
    h8 nah, nal, nb0h, nb0l, nb1h, nb1l;
    const bool more = (s + 1 < (DD / 4) / BK);
    if (more) {
      nah  = *(const h8*)(Ap  + (s + 1) * BK);
      nal  = *(const h8*)(Alp + (s + 1) * BK);
      nb0h = *(const h8*)(B0h + (s + 1) * BK);
      nb0l = *(const h8*)(B0l + (s + 1) * BK);
      nb1h = *(const h8*)(B1h + (s + 1) * BK);
      nb1l = *(const h8*)(B1l + (s + 1) * BK);
    }
    // per-acc product order hh, hl, lh (proven numerics)
    q0 = __builtin_amdgcn_mfma_f32_16x16x32_f16(cah, cb0h, q0, 0, 0, 0);
    q1 = __builtin_amdgcn_mfma_f32_16x16x32_f16(cah, cb1h, q1, 0, 0, 0);
    q0 = __builtin_amdgcn_mfma_f32_16x16x32_f16(cah, cb0l, q0, 0, 0, 0);
    q1 = __builtin_amdgcn_mfma_f32_16x16x32_f16(cah, cb1l, q1, 0, 0, 0);
    q0 = __builtin_amdgcn_mfma_f32_16x16x32_f16(cal, cb0h, q0, 0, 0, 0);
    q1 = __builtin_amdgcn_mfma_f32_16x16x32_f16(cal, cb1h, q1, 0, 0, 0);
    if (more) { cah = nah; cal = nal; cb0h = nb0h; cb0l = nb0l; cb1h = nb1h; cb1l = nb1l; }
  }

  float (*Qs)[16][33] = (float (*)[16][33])(&sbuf[0][0]);   // 8448 B alias, padded
  #pragma unroll
  for (int r = 0; r < 4; ++r) {
    Qs[wave][quad * 4 + r][r15]      = q0[r];
    Qs[wave][quad * 4 + r][16 + r15] = q1[r];
  }
  __syncthreads();
  float sA = Qs[0][nl][ml];
  sA += Qs[1][nl][ml]; sA += Qs[2][nl][ml]; sA += Qs[3][nl][ml];
  float sB = Qs[0][nl][ml + 16];
  sB += Qs[1][nl][ml + 16]; sB += Qs[2][nl][ml + 16]; sB += Qs[3][nl][ml + 16];
  const float cA = fast_tanh(sA);
  const float cB = fast_tanh(sB);
  __syncthreads();   // Qs dead; sbuf reused by phase 2

  // ---- phase 2: R6-frozen transcendental loop over this z's d-range
  const int n  = n0 + nl;
  const int mA = m0 + ml, mB = mA + 16;
  const int dbase = z * DRANGE;

  float4 aA = {0.f, 0.f, 0.f, 0.f};
  float4 aB = {0.f, 0.f, 0.f, 0.f};

  // staging: 64 rows (text 0..15 | kw2t 16..31 | kw3v 32..63) x 32 cols
  const int srow = tid >> 3;              // 0..31
  const int sc   = (tid & 7) << 2;        // 0,4,...,28
  const float* g1 = (srow < 16)
      ? &text[(size_t)(n0 + srow) * DD + dbase + sc]
      : &kw2t[(size_t)(n0 + srow - 16) * DD + dbase + sc];
  const float* g3 = &kw3v[(size_t)(m0 + srow) * DD + dbase + sc];
  const int w1 = srow * MLDW + sc;          // rows 0..31 (text | kw2t)
  const int w3 = (32 + srow) * MLDW + sc;   // rows 32..63 (kw3v, 32 rows)

  // prologue: stage chunk 0 into buffer 0
  float4 r1 = *(const float4*)g1;
  float4 r3 = *(const float4*)g3;
  int p = 0;
  *(float4*)&sbuf[0][w1] = r1;
  *(float4*)&sbuf[0][w3] = r3;
  __syncthreads();

  #pragma unroll 4
  for (int c = 0; c < DRANGE / DCH; ++c) {   // 12 chunks
    const bool more = (c + 1 < DRANGE / DCH);
    if (more) {  // prefetch next chunk; compute below hides latency
      r1 = *(const float4*)(g1 + (c + 1) * DCH);
      r3 = *(const float4*)(g3 + (c + 1) * DCH);
    }
    const float* bp = sbuf[p];
    #pragma unroll 4
    for (int j = 0; j < DCH; j += 4) {
      const float4 tv  = *(const float4*)&bp[nl * MLDW + j];
      const float4 w2v = *(const float4*)&bp[(16 + nl) * MLDW + j];
      const float4 w3A = *(const float4*)&bp[(32 + ml) * MLDW + j];
      const float4 w3B = *(const float4*)&bp[(48 + ml) * MLDW + j];
      aA.x = fmaf(tv.x, frcp(fexp(fmaf(w3A.x, cA, w2v.x)) + 1.0f), aA.x);
      aA.y = fmaf(tv.y, frcp(fexp(fmaf(w3A.y, cA, w2v.y)) + 1.0f), aA.y);
      aA.z = fmaf(tv.z, frcp(fexp(fmaf(w3A.z, cA, w2v.z)) + 1.0f), aA.z);
      aA.w = fmaf(tv.w, frcp(fexp(fmaf(w3A.w, cA, w2v.w)) + 1.0f), aA.w);
      aB.x = fmaf(tv.x, frcp(fexp(fmaf(w3B.x, cB, w2v.x)) + 1.0f), aB.x);
      aB.y = fmaf(tv.y, frcp(fexp(fmaf(w3B.y, cB, w2v.y)) + 1.0f), aB.y);
      aB.z = fmaf(tv.z, frcp(fexp(fmaf(w3B.z, cB, w2v.z)) + 1.0f), aB.z);
      aB.w = fmaf(tv.w, frcp(fexp(fmaf(w3B.w, cB, w2v.w)) + 1.0f), aB.w);
    }
    if (more) {
      const int q = p ^ 1;
      *(float4*)&sbuf[q][w1] = r1;
      *(float4*)&sbuf[q][w3] = r3;
    }
    __syncthreads();   // single barrier per chunk
    p ^= 1;
  }

  float* op = out + (size_t)n * MM;
  unsafeAtomicAdd(&op[mA], -2.0f * ((aA.x + aA.y) + (aA.z + aA.w)));
  unsafeAtomicAdd(&op[mB], -2.0f * ((aB.x + aB.y) + (aB.z + aB.w)));
}

// ---- launcher --------------------------------------------------------------
extern "C" void kernel_launch(void* const* d_in, const int* in_sizes, int n_in,
                              void* d_out, int out_size, void* d_ws, size_t ws_size,
                              hipStream_t stream) {
  const float* text   = (const float*)d_in[0];
  const float* visual = (const float*)d_in[1];
  const float* W1     = (const float*)d_in[2];
  const float* W2     = (const float*)d_in[3];
  const float* W3     = (const float*)d_in[4];
  float* out = (float*)d_out;

  // Workspace byte layout (14.25 MB, proven available):
  //   th/tl/vh/vl   : f16 hi/lo of text, visual   (4 x 768 KB)
  //   w1 h/l        : f16 hi/lo of W1 [d][j]      (2 x 1.125 MB, untransposed)
  //   w2t h/l       : f16 hi/lo of W2^T [j][k]    (2 x 1.125 MB)
  //   w3 h/l        : f16 hi/lo of W3 [j][k]      (2 x 1.125 MB)
  //   V1th/V1tl     : f16 hi/lo of V1t [m][d]     (2 x 768 KB)
  //   kw2t/kw3v     : fp32                        (2 x 1.5 MB)
  char* base = (char*)d_ws;
  ushort* th   = (ushort*)(base);
  ushort* tl   = (ushort*)(base + 786432);
  ushort* vh   = (ushort*)(base + 1572864);
  ushort* vl   = (ushort*)(base + 2359296);
  ushort* w1h  = (ushort*)(base + 3145728);
  ushort* w1l  = (ushort*)(base + 4325376);
  ushort* w2th = (ushort*)(base + 5505024);
  ushort* w2tl = (ushort*)(base + 6684672);
  ushort* w3h  = (ushort*)(base + 7864320);
  ushort* w3l  = (ushort*)(base + 9043968);
  ushort* V1th = (ushort*)(base + 10223616);
  ushort* V1tl = (ushort*)(base + 11010048);
  float*  kw2t = (float*) (base + 11796480);
  float*  kw3v = (float*) (base + 13369344);

  hipLaunchKernelGGL(prep_kernel, dim3(2752), dim3(256), 0, stream,
                     text, visual, W1, W2, W3,
                     th, tl, vh, vl, w3h, w3l, w1h, w1l, w2th, w2tl, out);
  hipLaunchKernelGGL(mfma1_kernel, dim3(DD / 64, NN / 32, 3), dim3(256), 0, stream,
                     th, tl, vh, vl, w1h, w1l, w2th, w2tl, w3h, w3l,
                     V1th, V1tl, kw2t, kw3v);
  hipLaunchKernelGGL(main_kernel, dim3(MM / 32, NN / 16, 2), dim3(256), 0, stream,
                     text, kw2t, kw3v, th, tl, V1th, V1tl, out);
}

// Round 12
// 127.516 us; speedup vs baseline: 1.0929x; 1.0322x over previous
//
#include <hip/hip_runtime.h>

// Problem dims (hard-coded in reference)
#define DD   768
#define NN   512
#define MM   512

#define PRE_K 2.88539008177792681472f   // 2*log2(e)

typedef _Float16 h8 __attribute__((ext_vector_type(8)));  // 8 f16 (4 VGPRs)
typedef __attribute__((ext_vector_type(4))) float f32x4;  // MFMA C/D
typedef __attribute__((ext_vector_type(2))) float f32x2;  // packed fp32 (v_pk_*)

__device__ __forceinline__ float fexp(float x) { return __builtin_amdgcn_exp2f(x); }
__device__ __forceinline__ float frcp(float x) { return __builtin_amdgcn_rcpf(x); }
// tanh(x) = 1 - 2/(1 + e^{2x}); saturates correctly via exp2->inf/0 + rcp.
__device__ __forceinline__ float fast_tanh(float x) {
  return 1.0f - 2.0f * frcp(fexp(PRE_K * x) + 1.0f);
}
// Ledger: R13 keep HW trans (Schraudolph ADDED full-rate slots). R17 mega-
// kernel catastrophic. R18 bounds(256,8) spills. R19(R6, BEST 131.1): main
// 44.8 @ occ 40 = trans floor for the SCALAR mix. R20 BK64 neutral. R21
// in-GEMM convert neutral. R22(R9): harness re-poison fill = 42us (fixed);
// gap ~3-4us/dispatch. R23/R24 (R10/R11): Q-fusion premium == support saving;
// three structures within 1.5us -> placement space flat. R25(this): R6 build
// + packed-f32 inner loop (v_pk_fma_f32 halves full-rate issue 48->24 cyc per
// j-group; trans untouched). Neutral-at-worst: if scalarized, codegen same.

// fp32 -> f16 hi/lo split (pair covers ~21 mantissa bits)
__device__ __forceinline__ void splitf(float x, ushort& h, ushort& l) {
  const _Float16 hh = (_Float16)x;
  const _Float16 ll = (_Float16)(x - (float)hh);
  h = __builtin_bit_cast(unsigned short, hh);
  l = __builtin_bit_cast(unsigned short, ll);
}

// ---- fused prep (R0 verbatim) ----------------------------------------------
// blocks [0,1344): elementwise f16 hi/lo split of text/visual/W3
// blocks [1344,2496): transpose+split W1/W2 -> [j][k]
// blocks [2496,2752): T-init — out[n,m] = T[n] = sum_d text[n,d]
__global__ __launch_bounds__(256) void prep_kernel(
    const float* __restrict__ text, const float* __restrict__ visual,
    const float* __restrict__ W1, const float* __restrict__ W2,
    const float* __restrict__ W3,
    ushort* __restrict__ th, ushort* __restrict__ tl,
    ushort* __restrict__ vh, ushort* __restrict__ vl,
    ushort* __restrict__ w3h, ushort* __restrict__ w3l,
    ushort* __restrict__ w1th, ushort* __restrict__ w1tl,
    ushort* __restrict__ w2th, ushort* __restrict__ w2tl,
    float* __restrict__ out)
{
  __shared__ float Lt[32][33];
  const int b = blockIdx.x;
  const int t = threadIdx.x;

  if (b < 1344) {
    const float* src; ushort *dh, *dl; size_t off;
    if (b < 384)      { src = text;   dh = th;  dl = tl;  off = (size_t)b * 1024; }
    else if (b < 768) { src = visual; dh = vh;  dl = vl;  off = (size_t)(b - 384) * 1024; }
    else              { src = W3;     dh = w3h; dl = w3l; off = (size_t)(b - 768) * 1024; }
    const size_t i = off + (size_t)t * 4;
    const float4 v = *(const float4*)&src[i];
    ushort4 h, l;
    splitf(v.x, h.x, l.x); splitf(v.y, h.y, l.y);
    splitf(v.z, h.z, l.z); splitf(v.w, h.w, l.w);
    *(ushort4*)&dh[i] = h;
    *(ushort4*)&dl[i] = l;
  } else if (b < 2496) {
    const int tt = b - 1344;
    const bool second = tt >= 576;
    const int tile = second ? tt - 576 : tt;
    const float* W = second ? W2 : W1;
    ushort* oh = second ? w2th : w1th;
    ushort* ol = second ? w2tl : w1tl;
    const int k0 = (tile / 24) * 32, j0 = (tile % 24) * 32;
    {
      const int k = t >> 3, j4 = (t & 7) * 4;
      const float4 v = *(const float4*)&W[(size_t)(k0 + k) * DD + j0 + j4];
      Lt[j4 + 0][k] = v.x; Lt[j4 + 1][k] = v.y;
      Lt[j4 + 2][k] = v.z; Lt[j4 + 3][k] = v.w;
    }
    __syncthreads();
    {
      const int j = t >> 3, k4 = (t & 7) * 4;
      ushort4 h, l;
      splitf(Lt[j][k4 + 0], h.x, l.x); splitf(Lt[j][k4 + 1], h.y, l.y);
      splitf(Lt[j][k4 + 2], h.z, l.z); splitf(Lt[j][k4 + 3], h.w, l.w);
      *(ushort4*)&oh[(size_t)(j0 + j) * DD + k0 + k4] = h;
      *(ushort4*)&ol[(size_t)(j0 + j) * DD + k0 + k4] = l;
    }
  } else {
    // T-init: rows n0, n0+1; out[row][:] = T[row]
    float* red = (float*)Lt;          // 258 floats needed, 1056 available
    const int u = b - 2496;
    const int n0 = u * 2;
    const int half = t >> 7;
    const int lt = t & 127;

    const float* tr = text + (size_t)(n0 + half) * DD;
    float s = 0.f;
    #pragma unroll
    for (int i = 0; i < DD / 128; ++i) s += tr[lt + i * 128];
    red[t] = s;
    __syncthreads();
    #pragma unroll
    for (int st = 64; st > 0; st >>= 1) {
      if (lt < st) red[t] += red[t + st];
      __syncthreads();
    }
    const float Tn = red[half << 7];
    float4 o; o.x = Tn; o.y = Tn; o.z = Tn; o.w = Tn;
    *(float4*)&out[(size_t)(n0 + half) * MM + lt * 4] = o;
  }
}

// ---- staged-LDS MFMA GEMM core, 32x64 tile + k0 (R6-proven) ----------------
#define BK   32
#define LROW 40            // padded LDS row stride (f16): 2-way banks, 16B-aligned
#define APL  (32 * LROW)   // one A plane (rows x LROW), in ushorts
#define BPL  (64 * LROW)   // one B plane

template <bool ALO>
__device__ __forceinline__ void gemm_core32(
    ushort* __restrict__ As, ushort* __restrict__ Bs,  // [2 buf][2 hi/lo][plane]
    const ushort* __restrict__ Ahg, const ushort* __restrict__ Alg,
    const ushort* __restrict__ Bhg, const ushort* __restrict__ Blg,
    int i0, int j0, int k0, int nsteps, f32x4* acc)
{
  const int tid = threadIdx.x;
  const int row = tid >> 2;             // 0..63 staging row (B); 0..31 for A
  const int ks8 = (tid & 3) * 8;        // 0,8,16,24 (f16)
  const bool doA = (row < 32);          // waves 0,1 stage A too (wave-uniform)
  const size_t ga = (size_t)(i0 + row) * DD + k0 + ks8;
  const size_t gb = (size_t)(j0 + row) * DD + k0 + ks8;
  const int lw = row * LROW + ks8;

  const int lane = tid & 63, wave = tid >> 6;
  const int r15 = lane & 15, quad = lane >> 4;
  const int wr = wave >> 1, wc = wave & 1;              // 2x2 wave grid
  const int fa = (wr * 16 + r15) * LROW + quad * 8;     // A frag offset
  const int fb = (wc * 32 + r15) * LROW + quad * 8;     // B frag base

  h8 pah, pal, pbh, pbl;
  if (doA) {
    pah = *(const h8*)(Ahg + ga);
    if (ALO) pal = *(const h8*)(Alg + ga);
  }
  pbh = *(const h8*)(Bhg + gb);
  pbl = *(const h8*)(Blg + gb);

  int p = 0;
  if (doA) {
    *(h8*)&As[lw] = pah;
    if (ALO) *(h8*)&As[APL + lw] = pal;
  }
  *(h8*)&Bs[lw] = pbh;
  *(h8*)&Bs[BPL + lw] = pbl;
  __syncthreads();

  for (int s = 0; s < nsteps; ++s) {
    const bool more = (s + 1 < nsteps);
    if (more) {  // issue next chunk's globals; MFMA below hides latency
      if (doA) {
        pah = *(const h8*)(Ahg + ga + (s + 1) * BK);
        if (ALO) pal = *(const h8*)(Alg + ga + (s + 1) * BK);
      }
      pbh = *(const h8*)(Bhg + gb + (s + 1) * BK);
      pbl = *(const h8*)(Blg + gb + (s + 1) * BK);
    }
    ushort* Ac = As + p * 2 * APL;
    ushort* Bc = Bs + p * 2 * BPL;
    const h8 a_h = *(const h8*)&Ac[fa];
    h8 a_l; if (ALO) a_l = *(const h8*)&Ac[APL + fa];
    h8 b_h[2], b_l[2];
    #pragma unroll
    for (int c = 0; c < 2; ++c) {
      b_h[c] = *(const h8*)&Bc[fb + c * 16 * LROW];
      b_l[c] = *(const h8*)&Bc[BPL + fb + c * 16 * LROW];
    }
    #pragma unroll
    for (int c = 0; c < 2; ++c)
      acc[c] = __builtin_amdgcn_mfma_f32_16x16x32_f16(a_h, b_h[c], acc[c], 0, 0, 0);
    #pragma unroll
    for (int c = 0; c < 2; ++c)
      acc[c] = __builtin_amdgcn_mfma_f32_16x16x32_f16(a_h, b_l[c], acc[c], 0, 0, 0);
    if (ALO) {
      #pragma unroll
      for (int c = 0; c < 2; ++c)
        acc[c] = __builtin_amdgcn_mfma_f32_16x16x32_f16(a_l, b_h[c], acc[c], 0, 0, 0);
    }
    if (more) {
      const int q = p ^ 1;
      ushort* An = As + q * 2 * APL;
      ushort* Bn = Bs + q * 2 * BPL;
      if (doA) {
        *(h8*)&An[lw] = pah;
        if (ALO) *(h8*)&An[APL + lw] = pal;
      }
      *(h8*)&Bn[lw] = pbh;
      *(h8*)&Bn[BPL + lw] = pbl;
    }
    __syncthreads();
    p ^= 1;
  }
}

// z=0: A=text@W1 -> Ah/Al(f16)  z=1: kw2t=PRE_K*text@W2  z=2: kw3v=PRE_K*visual@W3^T
// grid (DD/64, NN/32, 3) = (12, 16, 3) = 576 blocks.
__global__ __launch_bounds__(256) void mfma1_kernel(
    const ushort* __restrict__ th, const ushort* __restrict__ tl,
    const ushort* __restrict__ vh, const ushort* __restrict__ vl,
    const ushort* __restrict__ w1th, const ushort* __restrict__ w1tl,
    const ushort* __restrict__ w2th, const ushort* __restrict__ w2tl,
    const ushort* __restrict__ w3h, const ushort* __restrict__ w3l,
    ushort* __restrict__ Ah, ushort* __restrict__ Al,
    float* __restrict__ kw2t, float* __restrict__ kw3v)
{
  __shared__ ushort As[2 * 2 * APL];   // 10240 B
  __shared__ ushort Bs[2 * 2 * BPL];   // 20480 B

  const int z  = blockIdx.z;
  const int j0 = blockIdx.x * 64;
  const int i0 = blockIdx.y * 32;

  f32x4 acc[2];
  acc[0] = (f32x4){0.f, 0.f, 0.f, 0.f};
  acc[1] = (f32x4){0.f, 0.f, 0.f, 0.f};

  if (z == 0)
    gemm_core32<true >(As, Bs, th, tl, w1th, w1tl, i0, j0, 0, DD / BK, acc);
  else if (z == 1)
    gemm_core32<false>(As, Bs, th, tl, w2th, w2tl, i0, j0, 0, DD / BK, acc);
  else
    gemm_core32<false>(As, Bs, vh, vl, w3h,  w3l,  i0, j0, 0, DD / BK, acc);

  const int lane = threadIdx.x & 63, wave = threadIdx.x >> 6;
  const int r15 = lane & 15, quad = lane >> 4;
  const int wr = wave >> 1, wc = wave & 1;
  // C/D layout: col=lane&15 (B row j), row=quad*4+reg (A row i)
  if (z == 0) {
    #pragma unroll
    for (int c = 0; c < 2; ++c)
      #pragma unroll
      for (int r = 0; r < 4; ++r) {
        const size_t o = (size_t)(i0 + wr * 16 + quad * 4 + r) * DD
                       + j0 + wc * 32 + c * 16 + r15;
        splitf(acc[c][r], Ah[o], Al[o]);
      }
  } else {
    float* Out = (z == 1) ? kw2t : kw3v;
    #pragma unroll
    for (int c = 0; c < 2; ++c)
      #pragma unroll
      for (int r = 0; r < 4; ++r)
        Out[(size_t)(i0 + wr * 16 + quad * 4 + r) * DD + j0 + wc * 32 + c * 16 + r15] =
            acc[c][r] * PRE_K;
  }
}

// Q[z] = A @ visual^T over K quarter z.  grid (8, 16, 4) = 512 blocks (2/CU).
__global__ __launch_bounds__(256) void mfma2_kernel(
    const ushort* __restrict__ Ah, const ushort* __restrict__ Al,
    const ushort* __restrict__ vh, const ushort* __restrict__ vl,
    float* __restrict__ Q)
{
  __shared__ ushort As[2 * 2 * APL];
  __shared__ ushort Bs[2 * 2 * BPL];

  const int z  = blockIdx.z;
  const int j0 = blockIdx.x * 64;
  const int i0 = blockIdx.y * 32;

  f32x4 acc[2];
  acc[0] = (f32x4){0.f, 0.f, 0.f, 0.f};
  acc[1] = (f32x4){0.f, 0.f, 0.f, 0.f};
  gemm_core32<true>(As, Bs, Ah, Al, vh, vl, i0, j0, z * (DD / 4), (DD / 4) / BK, acc);

  const int lane = threadIdx.x & 63, wave = threadIdx.x >> 6;
  const int r15 = lane & 15, quad = lane >> 4;
  const int wr = wave >> 1, wc = wave & 1;
  float* Qp = Q + (size_t)z * NN * MM;
  #pragma unroll
  for (int c = 0; c < 2; ++c)
    #pragma unroll
    for (int r = 0; r < 4; ++r)
      Qp[(size_t)(i0 + wr * 16 + quad * 4 + r) * MM + j0 + wc * 32 + c * 16 + r15] =
          acc[c][r];
}

// ---- main fused kernel (R6 structure; inner loop on packed f32x2) ----------
// Per j-group: 24 full-rate scalar slots -> 12 v_pk slots (arg fma, +1 add,
// acc fma packed); 16 trans (exp/rcp) unchanged. Accumulator slot order
// preserved (aAL/aAH = old aA.xy/zw), so reductions are bit-identical.
#define DCH    32
#define DRANGE 192
#define MLDW   36

__global__ __launch_bounds__(256, 4) void main_kernel(
    const float* __restrict__ text, const float* __restrict__ kw2t,
    const float* __restrict__ kw3v, const float* __restrict__ Q,
    float* __restrict__ out)
{
  __shared__ float sbuf[2][64 * MLDW];   // 2 x 9216 B = 18432 B

  const int tid = threadIdx.x;
  const int nl = tid >> 4;
  const int ml = tid & 15;
  const int n0 = blockIdx.y * 16;
  const int m0 = blockIdx.x * 32;
  const int z  = blockIdx.z;
  const int n  = n0 + nl;
  const int mA = m0 + ml, mB = mA + 16;
  const int dbase = z * DRANGE;

  float cA = 0.f, cB = 0.f;
  #pragma unroll
  for (int zz = 0; zz < 4; ++zz) {
    const float* q = Q + (size_t)zz * NN * MM + (size_t)n * MM;
    cA += q[mA]; cB += q[mB];
  }
  cA = fast_tanh(cA); cB = fast_tanh(cB);
  const f32x2 cA2 = {cA, cA}, cB2 = {cB, cB};
  const f32x2 one2 = {1.0f, 1.0f};

  f32x2 aAL = {0.f, 0.f}, aAH = {0.f, 0.f};
  f32x2 aBL = {0.f, 0.f}, aBH = {0.f, 0.f};

  // staging: 64 rows (text 0..15 | kw2t 16..31 | kw3v 32..63) x 32 cols
  const int srow = tid >> 3;              // 0..31
  const int sc   = (tid & 7) << 2;        // 0,4,...,28
  const float* g1 = (srow < 16)
      ? &text[(size_t)(n0 + srow) * DD + dbase + sc]
      : &kw2t[(size_t)(n0 + srow - 16) * DD + dbase + sc];
  const float* g3 = &kw3v[(size_t)(m0 + srow) * DD + dbase + sc];
  const int w1 = srow * MLDW + sc;          // rows 0..31 (text | kw2t)
  const int w3 = (32 + srow) * MLDW + sc;   // rows 32..63 (kw3v, 32 rows)

  // prologue: stage chunk 0 into buffer 0
  float4 r1 = *(const float4*)g1;
  float4 r3 = *(const float4*)g3;
  int p = 0;
  *(float4*)&sbuf[0][w1] = r1;
  *(float4*)&sbuf[0][w3] = r3;
  __syncthreads();

  #pragma unroll
  for (int c = 0; c < DRANGE / DCH; ++c) {   // 6 chunks
    const bool more = (c + 1 < DRANGE / DCH);
    if (more) {  // prefetch next chunk; compute below hides latency
      r1 = *(const float4*)(g1 + (c + 1) * DCH);
      r3 = *(const float4*)(g3 + (c + 1) * DCH);
    }
    const float* bp = sbuf[p];
    #pragma unroll 4
    for (int j = 0; j < DCH; j += 4) {
      const f32x2 tvL  = *(const f32x2*)&bp[nl * MLDW + j];
      const f32x2 tvH  = *(const f32x2*)&bp[nl * MLDW + j + 2];
      const f32x2 w2L  = *(const f32x2*)&bp[(16 + nl) * MLDW + j];
      const f32x2 w2H  = *(const f32x2*)&bp[(16 + nl) * MLDW + j + 2];
      const f32x2 a3L  = *(const f32x2*)&bp[(32 + ml) * MLDW + j];
      const f32x2 a3H  = *(const f32x2*)&bp[(32 + ml) * MLDW + j + 2];
      const f32x2 b3L  = *(const f32x2*)&bp[(48 + ml) * MLDW + j];
      const f32x2 b3H  = *(const f32x2*)&bp[(48 + ml) * MLDW + j + 2];

      f32x2 gAL = a3L * cA2 + w2L;    // v_pk_fma_f32
      f32x2 gAH = a3H * cA2 + w2H;
      f32x2 gBL = b3L * cB2 + w2L;
      f32x2 gBH = b3H * cB2 + w2H;
      gAL.x = fexp(gAL.x); gAL.y = fexp(gAL.y);   // quarter-rate trans (scalar)
      gAH.x = fexp(gAH.x); gAH.y = fexp(gAH.y);
      gBL.x = fexp(gBL.x); gBL.y = fexp(gBL.y);
      gBH.x = fexp(gBH.x); gBH.y = fexp(gBH.y);
      gAL = gAL + one2;               // v_pk_add_f32
      gAH = gAH + one2;
      gBL = gBL + one2;
      gBH = gBH + one2;
      gAL.x = frcp(gAL.x); gAL.y = frcp(gAL.y);
      gAH.x = frcp(gAH.x); gAH.y = frcp(gAH.y);
      gBL.x = frcp(gBL.x); gBL.y = frcp(gBL.y);
      gBH.x = frcp(gBH.x); gBH.y = frcp(gBH.y);
      aAL = tvL * gAL + aAL;          // v_pk_fma_f32 accumulate
      aAH = tvH * gAH + aAH;
      aBL = tvL * gBL + aBL;
      aBH = tvH * gBH + aBH;
    }
    if (more) {
      const int q = p ^ 1;
      *(float4*)&sbuf[q][w1] = r1;
      *(float4*)&sbuf[q][w3] = r3;
    }
    __syncthreads();   // single barrier per chunk
    p ^= 1;
  }

  float* op = out + (size_t)n * MM;
  unsafeAtomicAdd(&op[mA], -2.0f * ((aAL.x + aAL.y) + (aAH.x + aAH.y)));
  unsafeAtomicAdd(&op[mB], -2.0f * ((aBL.x + aBL.y) + (aBH.x + aBH.y)));
}

// ---- launcher --------------------------------------------------------------
extern "C" void kernel_launch(void* const* d_in, const int* in_sizes, int n_in,
                              void* d_out, int out_size, void* d_ws, size_t ws_size,
                              hipStream_t stream) {
  const float* text   = (const float*)d_in[0];
  const float* visual = (const float*)d_in[1];
  const float* W1     = (const float*)d_in[2];
  const float* W2     = (const float*)d_in[3];
  const float* W3     = (const float*)d_in[4];
  float* out = (float*)d_out;

  // Workspace byte layout (peak 14.25 MB, proven available):
  //   th/tl/vh/vl : f16 hi/lo of text, visual     (4 x 768 KB)
  //   w1t/w2t h,l : f16 hi/lo of W1^T,W2^T [j][k] (4 x 1.125 MB)
  //   w3 h/l      : f16 hi/lo of W3 [j][k]        (2 x 1.125 MB)
  //   Ah/Al       : f16 hi/lo of A                (2 x 768 KB)
  //   kw2t/kw3v   : fp32                          (2 x 1.5 MB)
  // Overlay (stream-serial; sources dead before overwrite):
  //   Q (4 MB) -> w1th..w2tl  (dead after mfma1; mfma2 writes Q)
  char* base = (char*)d_ws;
  ushort* th   = (ushort*)(base);
  ushort* tl   = (ushort*)(base + 786432);
  ushort* vh   = (ushort*)(base + 1572864);
  ushort* vl   = (ushort*)(base + 2359296);
  ushort* w1th = (ushort*)(base + 3145728);
  ushort* w1tl = (ushort*)(base + 4325376);
  ushort* w2th = (ushort*)(base + 5505024);
  ushort* w2tl = (ushort*)(base + 6684672);
  ushort* w3h  = (ushort*)(base + 7864320);
  ushort* w3l  = (ushort*)(base + 9043968);
  ushort* Ah   = (ushort*)(base + 10223616);
  ushort* Al   = (ushort*)(base + 11010048);
  float*  kw2t = (float*) (base + 11796480);
  float*  kw3v = (float*) (base + 13369344);
  float*  Q    = (float*) (base + 3145728);   // 4 MB over w1t/w2t

  hipLaunchKernelGGL(prep_kernel, dim3(2752), dim3(256), 0, stream,
                     text, visual, W1, W2, W3,
                     th, tl, vh, vl, w3h, w3l, w1th, w1tl, w2th, w2tl, out);
  hipLaunchKernelGGL(mfma1_kernel, dim3(DD / 64, NN / 32, 3), dim3(256), 0, stream,
                     th, tl, vh, vl, w1th, w1tl, w2th, w2tl, w3h, w3l,
                     Ah, Al, kw2t, kw3v);
  hipLaunchKernelGGL(mfma2_kernel, dim3(MM / 64, NN / 32, 4), dim3(256), 0, stream,
                     Ah, Al, vh, vl, Q);
  hipLaunchKernelGGL(main_kernel, dim3(MM / 32, NN / 16, 4), dim3(256), 0, stream,
                     text, kw2t, kw3v, Q, out);
}